// Round 5
// baseline (625.227 us; speedup 1.0000x reference)
//
#include <hip/hip_runtime.h>

typedef unsigned short u16;
typedef unsigned int u32;
using f32x4  = __attribute__((ext_vector_type(4))) float;
using bf16x8 = __attribute__((ext_vector_type(8))) __bf16;
using u16x4  = __attribute__((ext_vector_type(4))) unsigned short;
using u16x8  = __attribute__((ext_vector_type(8))) unsigned short;
using u32x4  = __attribute__((ext_vector_type(4))) unsigned int;

#define MFMA16(a,b,c) __builtin_amdgcn_mfma_f32_16x16x32_bf16(a,b,c,0,0,0)

__device__ __forceinline__ u16 f2bf(float f) {
  unsigned u = __builtin_bit_cast(unsigned, f);
  u += 0x7FFFu + ((u >> 16) & 1u);
  return (u16)(u >> 16);
}
__device__ __forceinline__ u32 pk2(float a, float b) {
  return (u32)f2bf(a) | ((u32)f2bf(b) << 16);
}

__device__ __forceinline__ void gld_lds16(const void* g, void* l) {
  __builtin_amdgcn_global_load_lds(
      (const __attribute__((address_space(1))) unsigned*)g,
      (__attribute__((address_space(3))) unsigned*)l, 16, 0, 0);
}

// ---------------- fp32 -> bf16 conversion (nt loads: read-once stream) -------
__global__ __launch_bounds__(256) void cvt_f32_bf16(
    const float* __restrict__ in, u16* __restrict__ out, int n8) {
  int stride = gridDim.x * blockDim.x;
  for (int i = blockIdx.x * blockDim.x + threadIdx.x; i < n8; i += stride) {
    long e = (long)i * 8;
    f32x4 a = __builtin_nontemporal_load((const f32x4*)(in + e));
    f32x4 b = __builtin_nontemporal_load((const f32x4*)(in + e + 4));
    u16x8 r;
    r[0] = f2bf(a[0]); r[1] = f2bf(a[1]); r[2] = f2bf(a[2]); r[3] = f2bf(a[3]);
    r[4] = f2bf(b[0]); r[5] = f2bf(b[1]); r[6] = f2bf(b[2]); r[7] = f2bf(b[3]);
    *(u16x8*)(out + e) = r;  // temporal: GEMM reads this soon
  }
}

// ---------------- 256x256 8-phase bf16 GEMM: C = A * B^T + bias --------------
// A [4096][K=4096], Bw [N][4096] row-major (K inner). 8 waves (2M x 4N),
// BK=64, 128 KiB LDS double-buffer, counted vmcnt(4), T2 swizzle, T5 setprio.
// ROUTE==1: N=6144; cols<5120 -> qkv bf16 (nt), cols>=5120 -> V^T bf16.
// ROUTE==0: N=4096; fp32 out (nt).
template <int ROUTE>
__global__ __launch_bounds__(512, 2) void gemm256(
    const u16* __restrict__ A, const u16* __restrict__ Bw,
    const float* __restrict__ bias,
    u16* __restrict__ qkv, u16* __restrict__ vT, float* __restrict__ outF,
    int NBN) {
  extern __shared__ char sm[];  // [2][ A 32K | B 32K ] = 131072 B
  constexpr int K = 4096, NT = K / 64;
  const int tid = threadIdx.x;

  // T1: XCD-aware block swizzle (gridDim.x % 8 == 0 guaranteed by launcher)
  const int nwg = gridDim.x;
  const int bid = blockIdx.x;
  const int nb = (bid & 7) * (nwg >> 3) + (bid >> 3);
  const int m0 = (nb / NBN) * 256;
  const int n0 = (nb % NBN) * 256;

  const int wid = tid >> 6, lane = tid & 63;
  const int wm = wid >> 2, wn = wid & 3;
  const int lr = lane & 15, lk = lane >> 4;

  // ---- staging: linear LDS dest + pre-swizzled global source (rule 21) ----
  auto stA = [&](int buf, int kt, int h) {
    char* dst = sm + buf * 65536 + h * 16384;
    const int k0 = kt * 64;
#pragma unroll
    for (int i = 0; i < 2; ++i) {
      int p = (i * 512 + tid) * 16;
      int row = p >> 7, cb = p & 127;
      gld_lds16(A + (size_t)(m0 + h * 128 + row) * K + k0 +
                    ((cb ^ ((row & 7) << 4)) >> 1),
                dst + p);
    }
  };
  auto stB = [&](int buf, int kt, int h) {
    char* dst = sm + buf * 65536 + 32768 + h * 16384;
    const int k0 = kt * 64;
#pragma unroll
    for (int i = 0; i < 2; ++i) {
      int p = (i * 512 + tid) * 16;
      int row = p >> 7, cb = p & 127;
      gld_lds16(Bw + (size_t)(n0 + h * 128 + row) * K + k0 +
                    ((cb ^ ((row & 7) << 4)) >> 1),
                dst + p);
    }
  };

  // fragment addressing (swizzled read side)
  const int swz = (lr & 7) << 4;
  const int rowOff = lr * 128;
  const int ck0 = (lk * 16) ^ swz;
  const int ck1 = (64 + lk * 16) ^ swz;
  const int bRow0 = (wn & 1) * 64;

  f32x4 acc[8][4] = {};
  bf16x8 bfr[4][2];

  // ---- prologue: t0 all 4 halves + t1.B0,B1 ; vmcnt(4) -> t0 landed ----
  stA(0, 0, 0); stA(0, 0, 1); stB(0, 0, 0); stB(0, 0, 1);
  stB(1, 1, 0); stB(1, 1, 1);
  asm volatile("s_waitcnt vmcnt(4)" ::: "memory");
  asm volatile("s_barrier" ::: "memory");

  for (int t = 0; t < NT; ++t) {
    const int buf = t & 1;
    const char* aB = sm + buf * 65536 + wm * 16384;
    const char* bB = sm + buf * 65536 + 32768 + (wn >> 1) * 16384;

    // ================= phase 1: B all + A quadrant 0 =================
    {
      bf16x8 afr[2][2];
#pragma unroll
      for (int n = 0; n < 4; ++n) {
        const char* r = bB + (bRow0 + n * 16) * 128 + rowOff;
        bfr[n][0] = *(const bf16x8*)(r + ck0);
        bfr[n][1] = *(const bf16x8*)(r + ck1);
      }
#pragma unroll
      for (int mm = 0; mm < 2; ++mm) {
        const char* r = aB + (mm * 16) * 128 + rowOff;
        afr[mm][0] = *(const bf16x8*)(r + ck0);
        afr[mm][1] = *(const bf16x8*)(r + ck1);
      }
      if (t + 1 < NT) stA(buf ^ 1, t + 1, 0);
      asm volatile("s_barrier" ::: "memory");
      asm volatile("s_waitcnt lgkmcnt(0)" ::: "memory");
      __builtin_amdgcn_sched_barrier(0);
      __builtin_amdgcn_s_setprio(1);
#pragma unroll
      for (int mm = 0; mm < 2; ++mm)
#pragma unroll
        for (int n = 0; n < 4; ++n) {
          acc[mm][n] = MFMA16(afr[mm][0], bfr[n][0], acc[mm][n]);
          acc[mm][n] = MFMA16(afr[mm][1], bfr[n][1], acc[mm][n]);
        }
      __builtin_amdgcn_s_setprio(0);
      asm volatile("s_barrier" ::: "memory");
    }
    // ================= phases 2-4: A quadrants 1-3 =================
#pragma unroll
    for (int q = 1; q < 4; ++q) {
      bf16x8 afr[2][2];
#pragma unroll
      for (int mm = 0; mm < 2; ++mm) {
        const char* r = aB + ((q * 2 + mm) * 16) * 128 + rowOff;
        afr[mm][0] = *(const bf16x8*)(r + ck0);
        afr[mm][1] = *(const bf16x8*)(r + ck1);
      }
      if (q == 1) { if (t + 1 < NT) stA(buf ^ 1, t + 1, 1); }
      else if (q == 2) { if (t + 2 < NT) stB(buf, t + 2, 0); }
      else { if (t + 2 < NT) stB(buf, t + 2, 1); }
      asm volatile("s_barrier" ::: "memory");
      asm volatile("s_waitcnt lgkmcnt(0)" ::: "memory");
      __builtin_amdgcn_sched_barrier(0);
      __builtin_amdgcn_s_setprio(1);
#pragma unroll
      for (int mm = 0; mm < 2; ++mm)
#pragma unroll
        for (int n = 0; n < 4; ++n) {
          acc[q * 2 + mm][n] = MFMA16(afr[mm][0], bfr[n][0], acc[q * 2 + mm][n]);
          acc[q * 2 + mm][n] = MFMA16(afr[mm][1], bfr[n][1], acc[q * 2 + mm][n]);
        }
      __builtin_amdgcn_s_setprio(0);
      if (q == 3) {  // T4: counted drain once per K-tile, never 0 mid-loop
        if (t + 2 < NT)      asm volatile("s_waitcnt vmcnt(4)" ::: "memory");
        else if (t + 1 < NT) asm volatile("s_waitcnt vmcnt(0)" ::: "memory");
      }
      asm volatile("s_barrier" ::: "memory");
    }
  }

  // ---- epilogue ----
#pragma unroll
  for (int m = 0; m < 8; ++m) {
#pragma unroll
    for (int n = 0; n < 4; ++n) {
      const int col = n0 + wn * 64 + n * 16 + lr;
      const float bv = bias[col];
#pragma unroll
      for (int j = 0; j < 4; ++j) {
        const int row = m0 + wm * 128 + m * 16 + lk * 4 + j;
        const float v = acc[m][n][j] + bv;
        if (ROUTE == 0) {
          __builtin_nontemporal_store(v, &outF[(size_t)row * 4096 + col]);
        } else {
          if (col < 5120) {
            __builtin_nontemporal_store(f2bf(v), &qkv[(size_t)row * 6144 + col]);
          } else {
            int cv = col - 5120, hh = cv >> 7, d = cv & 127;
            int bb = row >> 11, s = row & 2047;
            vT[((size_t)((bb * 8 + hh) * 128 + d)) * 2048 + s] = f2bf(v);
          }
        }
      }
    }
  }
}

// ---------------- causal GQA flash attention (swapped-QK^T, in-reg softmax) ----
__global__ __launch_bounds__(256, 2) void attn_fwd(
    const u16* __restrict__ qkv, const u16* __restrict__ vT,
    u16* __restrict__ out) {
  __shared__ __align__(16) char smem[65536];  // dbuf: [buf]{K 16K, V 16K}

  const int tid = threadIdx.x;
  const int qt = blockIdx.x, h = blockIdx.y, b = blockIdx.z;
  const int hkv = h >> 2;
  const int q0 = qt * 128;
  const int wv = tid >> 6, lane = tid & 63;
  const int lr = lane & 15, lk = lane >> 4;

  auto stage = [&](int buf, int t) {
    const int kv0 = t * 64;
    char* kb_ = smem + buf * 32768;
    char* vb_ = kb_ + 16384;
#pragma unroll
    for (int i = 0; i < 4; ++i) {
      int c = i * 256 + tid, p = c * 16;
      int row = p >> 8, colb = (p & 255) ^ ((row & 7) << 4);
      gld_lds16(qkv + (size_t)(b * 2048 + kv0 + row) * 6144 + 4096 + hkv * 128 + (colb >> 1),
                kb_ + p);
    }
#pragma unroll
    for (int i = 0; i < 4; ++i) {
      int c = i * 256 + tid, p = c * 16;
      int row = p >> 7, colb = (p & 127) ^ ((row & 7) << 4);
      gld_lds16(vT + (size_t)((b * 8 + hkv) * 128 + row) * 2048 + kv0 + (colb >> 1),
                vb_ + p);
    }
  };

  bf16x8 qf[2][4];
#pragma unroll
  for (int qs = 0; qs < 2; ++qs) {
    const u16* qp = qkv + (size_t)(b * 2048 + q0 + wv * 32 + qs * 16 + lr) * 6144 +
                    h * 128 + lk * 8;
#pragma unroll
    for (int dc = 0; dc < 4; ++dc) qf[qs][dc] = *(const bf16x8*)(qp + dc * 32);
  }

  f32x4 o[2][8] = {};
  float mrun[2] = {-3.0e38f, -3.0e38f};
  float lsum[2] = {0.f, 0.f};
  const float sc = 0.08838834764831845f;

  const int nt = 2 * qt + 2;
  const int qbase_w = q0 + wv * 32;
  const int lkA = lr + 16 * (2 * (lk & 1) + (lk >> 1));
  const int lkB = lkA ^ 16;

  stage(0, 0);
  __syncthreads();
  for (int t = 0; t < nt; ++t) {
    const int buf = t & 1;
    if (t + 1 < nt) stage(buf ^ 1, t + 1);
    const int kv0 = t * 64;
    if (kv0 <= qbase_w + 31) {
      const char* kb_ = smem + buf * 32768;
      const char* vb_ = kb_ + 16384;

      f32x4 s[4][2];
#pragma unroll
      for (int cc = 0; cc < 4; ++cc) {
        const int krow = cc * 16 + lr;
        f32x4 a0 = {0.f, 0.f, 0.f, 0.f}, a1 = {0.f, 0.f, 0.f, 0.f};
#pragma unroll
        for (int dc = 0; dc < 4; ++dc) {
          bf16x8 kb = *(const bf16x8*)(kb_ + (krow << 8) +
                                       ((dc * 64 + lk * 16) ^ ((krow & 7) << 4)));
          a0 = MFMA16(kb, qf[0][dc], a0);
          a1 = MFMA16(kb, qf[1][dc], a1);
        }
        s[cc][0] = a0; s[cc][1] = a1;
      }

      const bool maskt = (kv0 + 63 > qbase_w);
#pragma unroll
      for (int cc = 0; cc < 4; ++cc)
#pragma unroll
        for (int qs = 0; qs < 2; ++qs)
#pragma unroll
          for (int j = 0; j < 4; ++j) {
            float v = s[cc][qs][j] * sc;
            if (maskt) {
              int kg = kv0 + cc * 16 + lk * 4 + j;
              int qg = qbase_w + qs * 16 + lr;
              if (kg > qg) v = -1.0e30f;
            }
            s[cc][qs][j] = v;
          }

      bf16x8 pfrag[2][2];
#pragma unroll
      for (int qs = 0; qs < 2; ++qs) {
        float mt = s[0][qs][0];
#pragma unroll
        for (int cc = 0; cc < 4; ++cc)
#pragma unroll
          for (int j = 0; j < 4; ++j) mt = fmaxf(mt, s[cc][qs][j]);
        mt = fmaxf(mt, __shfl_xor(mt, 16, 64));
        mt = fmaxf(mt, __shfl_xor(mt, 32, 64));
        const float mn = fmaxf(mrun[qs], mt);
        const float al = __expf(mrun[qs] - mn);
        mrun[qs] = mn;
        lsum[qs] *= al;
#pragma unroll
        for (int dc = 0; dc < 8; ++dc)
#pragma unroll
          for (int j = 0; j < 4; ++j) o[qs][dc][j] *= al;

        u32 pb[4][2];
        float ls = 0.f;
#pragma unroll
        for (int cc = 0; cc < 4; ++cc) {
          float p0 = __expf(s[cc][qs][0] - mn);
          float p1 = __expf(s[cc][qs][1] - mn);
          float p2 = __expf(s[cc][qs][2] - mn);
          float p3 = __expf(s[cc][qs][3] - mn);
          ls += (p0 + p1) + (p2 + p3);
          pb[cc][0] = pk2(p0, p1);
          pb[cc][1] = pk2(p2, p3);
        }
        lsum[qs] += ls;

#pragma unroll
        for (int ks = 0; ks < 2; ++ks) {
          const u32 e10 = (lk & 1) ? pb[ks * 2 + 1][0] : pb[ks * 2][0];
          const u32 e11 = (lk & 1) ? pb[ks * 2 + 1][1] : pb[ks * 2][1];
          const u32 e30 = (lk & 1) ? pb[ks * 2][0] : pb[ks * 2 + 1][0];
          const u32 e31 = (lk & 1) ? pb[ks * 2][1] : pb[ks * 2 + 1][1];
          const u32 r1 = __shfl((int)e10, lkA, 64);
          const u32 r2 = __shfl((int)e11, lkA, 64);
          const u32 r3 = __shfl((int)e30, lkB, 64);
          const u32 r4 = __shfl((int)e31, lkB, 64);
          u32x4 w;
          w[0] = (lk >> 1) ? r3 : r1;
          w[1] = (lk >> 1) ? r4 : r2;
          w[2] = (lk >> 1) ? r1 : r3;
          w[3] = (lk >> 1) ? r2 : r4;
          pfrag[qs][ks] = __builtin_bit_cast(bf16x8, w);
        }
      }

#pragma unroll
      for (int dc = 0; dc < 8; ++dc) {
        const int vrow = dc * 16 + lr;
#pragma unroll
        for (int ks = 0; ks < 2; ++ks) {
          bf16x8 vb = *(const bf16x8*)(vb_ + (vrow << 7) +
                                       ((ks * 64 + lk * 16) ^ ((vrow & 7) << 4)));
          o[0][dc] = MFMA16(vb, pfrag[0][ks], o[0][dc]);
          o[1][dc] = MFMA16(vb, pfrag[1][ks], o[1][dc]);
        }
      }
    }
    __syncthreads();
  }

  float rls[2];
#pragma unroll
  for (int qs = 0; qs < 2; ++qs) {
    float l = lsum[qs];
    l += __shfl_xor(l, 16, 64);
    l += __shfl_xor(l, 32, 64);
    rls[qs] = 1.0f / l;
  }
#pragma unroll
  for (int qs = 0; qs < 2; ++qs) {
    const int ql = wv * 32 + qs * 16 + lr;
#pragma unroll
    for (int dc = 0; dc < 8; ++dc) {
      u16x4 w;
#pragma unroll
      for (int j = 0; j < 4; ++j) w[j] = f2bf(o[qs][dc][j] * rls[qs]);
      *(u16x4*)(smem + ql * 256 + (((dc * 32 + lk * 8)) ^ ((ql & 7) << 4))) = w;
    }
  }
  __syncthreads();
#pragma unroll
  for (int i = 0; i < 8; ++i) {
    int c = i * 256 + tid;
    int row = c >> 4, ch = c & 15;
    u16x8 v = *(u16x8*)(smem + row * 256 + ((ch * 16) ^ ((row & 7) << 4)));
    *(u16x8*)(out + (size_t)(b * 2048 + q0 + row) * 4096 + h * 128 + ch * 8) = v;
  }
}

// ---------------- launcher ----------------
extern "C" void kernel_launch(void* const* d_in, const int* in_sizes, int n_in,
                              void* d_out, int out_size, void* d_ws, size_t ws_size,
                              hipStream_t stream) {
  const float* x  = (const float*)d_in[0];
  const float* w1 = (const float*)d_in[2];
  const float* b1 = (const float*)d_in[3];
  const float* w2 = (const float*)d_in[4];
  const float* b2 = (const float*)d_in[5];
  float* out = (float*)d_out;

  char* ws = (char*)d_ws;
  u16* xb   = (u16*)(ws);                  // x bf16      [4096][4096]
  u16* w1b  = (u16*)(ws + 33554432ul);     // Wqkv bf16   [6144][4096]
  u16* w2b  = (u16*)(ws + 83886080ul);     // out_w bf16  [4096][4096]
  u16* qkv  = (u16*)(ws + 117440512ul);    // qkv bf16    [4096][6144]
  u16* vT   = (u16*)(ws + 167772160ul);    // V^T bf16    [2][8][128][2048]
  u16* attnb = xb;                         // alias: x dead after GEMM1

  (void)hipFuncSetAttribute(reinterpret_cast<const void*>(gemm256<1>),
                            hipFuncAttributeMaxDynamicSharedMemorySize, 131072);
  (void)hipFuncSetAttribute(reinterpret_cast<const void*>(gemm256<0>),
                            hipFuncAttributeMaxDynamicSharedMemorySize, 131072);

  cvt_f32_bf16<<<2048, 256, 0, stream>>>(x,  xb,  16777216 / 8);
  cvt_f32_bf16<<<2048, 256, 0, stream>>>(w1, w1b, 25165824 / 8);
  gemm256<1><<<384, 512, 131072, stream>>>(xb, w1b, b1, qkv, vT, nullptr, 24);
  cvt_f32_bf16<<<2048, 256, 0, stream>>>(w2, w2b, 16777216 / 8);
  attn_fwd<<<dim3(16, 32, 2), 256, 0, stream>>>(qkv, vT, attnb);
  gemm256<0><<<256, 512, 131072, stream>>>(attnb, w2b, b2, nullptr, nullptr, out, 16);
}

// Round 6
// 606.191 us; speedup vs baseline: 1.0314x; 1.0314x over previous
//
#include <hip/hip_runtime.h>

typedef unsigned short u16;
typedef unsigned int u32;
using f32x4  = __attribute__((ext_vector_type(4))) float;
using bf16x8 = __attribute__((ext_vector_type(8))) __bf16;
using u16x4  = __attribute__((ext_vector_type(4))) unsigned short;
using u16x8  = __attribute__((ext_vector_type(8))) unsigned short;
using u32x4  = __attribute__((ext_vector_type(4))) unsigned int;

#define MFMA16(a,b,c) __builtin_amdgcn_mfma_f32_16x16x32_bf16(a,b,c,0,0,0)

__device__ __forceinline__ u16 f2bf(float f) {
  unsigned u = __builtin_bit_cast(unsigned, f);
  u += 0x7FFFu + ((u >> 16) & 1u);
  return (u16)(u >> 16);
}
__device__ __forceinline__ u32 pk2(float a, float b) {
  return (u32)f2bf(a) | ((u32)f2bf(b) << 16);
}

__device__ __forceinline__ void gld_lds16(const void* g, void* l) {
  __builtin_amdgcn_global_load_lds(
      (const __attribute__((address_space(1))) unsigned*)g,
      (__attribute__((address_space(3))) unsigned*)l, 16, 0, 0);
}

// ---------------- fp32 -> bf16 conversion (nt loads: read-once stream) -------
__global__ __launch_bounds__(256) void cvt_f32_bf16(
    const float* __restrict__ in, u16* __restrict__ out, int n8) {
  int stride = gridDim.x * blockDim.x;
  for (int i = blockIdx.x * blockDim.x + threadIdx.x; i < n8; i += stride) {
    long e = (long)i * 8;
    f32x4 a = __builtin_nontemporal_load((const f32x4*)(in + e));
    f32x4 b = __builtin_nontemporal_load((const f32x4*)(in + e + 4));
    u16x8 r;
    r[0] = f2bf(a[0]); r[1] = f2bf(a[1]); r[2] = f2bf(a[2]); r[3] = f2bf(a[3]);
    r[4] = f2bf(b[0]); r[5] = f2bf(b[1]); r[6] = f2bf(b[2]); r[7] = f2bf(b[3]);
    *(u16x8*)(out + e) = r;  // temporal: GEMM reads this soon
  }
}

// ---------------- 256x256 8-phase bf16 GEMM: C = A * B^T + bias --------------
// A [4096][K=4096], Bw [N][4096] row-major (K inner). 8 waves (2M x 4N),
// BK=64, 128 KiB LDS double-buffer, counted vmcnt(4), T2 swizzle, T5 setprio.
// XCD-region mapping: bid&7 = XCD; each XCD owns an 8M x (NBN/4)N region so
// its 32 co-resident blocks share 8 A-panels + <=6 B-panels (L2-resident
// K-slice footprint ~900 KB < 4 MB) -> L3 fetch once per XCD per slice.
// ROUTE==1: N=6144; cols<5120 -> qkv bf16, cols>=5120 -> V^T bf16.
// ROUTE==0: N=4096; fp32 out.
template <int ROUTE>
__global__ __launch_bounds__(512, 2) void gemm256(
    const u16* __restrict__ A, const u16* __restrict__ Bw,
    const float* __restrict__ bias,
    u16* __restrict__ qkv, u16* __restrict__ vT, float* __restrict__ outF,
    int NBN) {
  extern __shared__ char sm[];  // [2][ A 32K | B 32K ] = 131072 B
  constexpr int K = 4096, NT = K / 64;
  const int tid = threadIdx.x;

  // XCD-region block mapping (requires M/256==16, NBN%4==0; holds here)
  const int bid = blockIdx.x;
  const int xcd = bid & 7;
  const int idx = bid >> 3;
  const int rm = idx & 7;          // 8 M-tiles per region
  const int rn = idx >> 3;         // region-local N-col
  const int m0 = ((xcd >> 2) * 8 + rm) * 256;
  const int n0 = ((xcd & 3) * (NBN >> 2) + rn) * 256;

  const int wid = tid >> 6, lane = tid & 63;
  const int wm = wid >> 2, wn = wid & 3;
  const int lr = lane & 15, lk = lane >> 4;

  // ---- staging: linear LDS dest + pre-swizzled global source (rule 21) ----
  auto stA = [&](int buf, int kt, int h) {
    char* dst = sm + buf * 65536 + h * 16384;
    const int k0 = kt * 64;
#pragma unroll
    for (int i = 0; i < 2; ++i) {
      int p = (i * 512 + tid) * 16;
      int row = p >> 7, cb = p & 127;
      gld_lds16(A + (size_t)(m0 + h * 128 + row) * K + k0 +
                    ((cb ^ ((row & 7) << 4)) >> 1),
                dst + p);
    }
  };
  auto stB = [&](int buf, int kt, int h) {
    char* dst = sm + buf * 65536 + 32768 + h * 16384;
    const int k0 = kt * 64;
#pragma unroll
    for (int i = 0; i < 2; ++i) {
      int p = (i * 512 + tid) * 16;
      int row = p >> 7, cb = p & 127;
      gld_lds16(Bw + (size_t)(n0 + h * 128 + row) * K + k0 +
                    ((cb ^ ((row & 7) << 4)) >> 1),
                dst + p);
    }
  };

  // fragment addressing (swizzled read side)
  const int swz = (lr & 7) << 4;
  const int rowOff = lr * 128;
  const int ck0 = (lk * 16) ^ swz;
  const int ck1 = (64 + lk * 16) ^ swz;
  const int bRow0 = (wn & 1) * 64;

  f32x4 acc[8][4] = {};
  bf16x8 bfr[4][2];

  // ---- prologue: t0 all 4 halves + t1.B0,B1 ; vmcnt(4) -> t0 landed ----
  stA(0, 0, 0); stA(0, 0, 1); stB(0, 0, 0); stB(0, 0, 1);
  stB(1, 1, 0); stB(1, 1, 1);
  asm volatile("s_waitcnt vmcnt(4)" ::: "memory");
  asm volatile("s_barrier" ::: "memory");

  for (int t = 0; t < NT; ++t) {
    const int buf = t & 1;
    const char* aB = sm + buf * 65536 + wm * 16384;
    const char* bB = sm + buf * 65536 + 32768 + (wn >> 1) * 16384;

    // ================= phase 1: B all + A quadrant 0 =================
    {
      bf16x8 afr[2][2];
#pragma unroll
      for (int n = 0; n < 4; ++n) {
        const char* r = bB + (bRow0 + n * 16) * 128 + rowOff;
        bfr[n][0] = *(const bf16x8*)(r + ck0);
        bfr[n][1] = *(const bf16x8*)(r + ck1);
      }
#pragma unroll
      for (int mm = 0; mm < 2; ++mm) {
        const char* r = aB + (mm * 16) * 128 + rowOff;
        afr[mm][0] = *(const bf16x8*)(r + ck0);
        afr[mm][1] = *(const bf16x8*)(r + ck1);
      }
      if (t + 1 < NT) stA(buf ^ 1, t + 1, 0);
      asm volatile("s_barrier" ::: "memory");
      __builtin_amdgcn_s_setprio(1);
#pragma unroll
      for (int mm = 0; mm < 2; ++mm)
#pragma unroll
        for (int n = 0; n < 4; ++n) {
          acc[mm][n] = MFMA16(afr[mm][0], bfr[n][0], acc[mm][n]);
          acc[mm][n] = MFMA16(afr[mm][1], bfr[n][1], acc[mm][n]);
        }
      __builtin_amdgcn_s_setprio(0);
      asm volatile("s_barrier" ::: "memory");
    }
    // ================= phases 2-4: A quadrants 1-3 =================
#pragma unroll
    for (int q = 1; q < 4; ++q) {
      bf16x8 afr[2][2];
#pragma unroll
      for (int mm = 0; mm < 2; ++mm) {
        const char* r = aB + ((q * 2 + mm) * 16) * 128 + rowOff;
        afr[mm][0] = *(const bf16x8*)(r + ck0);
        afr[mm][1] = *(const bf16x8*)(r + ck1);
      }
      if (q == 1) { if (t + 1 < NT) stA(buf ^ 1, t + 1, 1); }
      else if (q == 2) { if (t + 2 < NT) stB(buf, t + 2, 0); }
      else { if (t + 2 < NT) stB(buf, t + 2, 1); }
      asm volatile("s_barrier" ::: "memory");
      __builtin_amdgcn_s_setprio(1);
#pragma unroll
      for (int mm = 0; mm < 2; ++mm)
#pragma unroll
        for (int n = 0; n < 4; ++n) {
          acc[q * 2 + mm][n] = MFMA16(afr[mm][0], bfr[n][0], acc[q * 2 + mm][n]);
          acc[q * 2 + mm][n] = MFMA16(afr[mm][1], bfr[n][1], acc[q * 2 + mm][n]);
        }
      __builtin_amdgcn_s_setprio(0);
      if (q == 3) {  // T4: counted drain once per K-tile, never 0 mid-loop
        if (t + 2 < NT)      asm volatile("s_waitcnt vmcnt(4)" ::: "memory");
        else if (t + 1 < NT) asm volatile("s_waitcnt vmcnt(0)" ::: "memory");
      }
      asm volatile("s_barrier" ::: "memory");
    }
  }

  // ---- epilogue ----
#pragma unroll
  for (int m = 0; m < 8; ++m) {
#pragma unroll
    for (int n = 0; n < 4; ++n) {
      const int col = n0 + wn * 64 + n * 16 + lr;
      const float bv = bias[col];
#pragma unroll
      for (int j = 0; j < 4; ++j) {
        const int row = m0 + wm * 128 + m * 16 + lk * 4 + j;
        const float v = acc[m][n][j] + bv;
        if (ROUTE == 0) {
          outF[(size_t)row * 4096 + col] = v;
        } else {
          if (col < 5120) {
            qkv[(size_t)row * 6144 + col] = f2bf(v);
          } else {
            int cv = col - 5120, hh = cv >> 7, d = cv & 127;
            int bb = row >> 11, s = row & 2047;
            vT[((size_t)((bb * 8 + hh) * 128 + d)) * 2048 + s] = f2bf(v);
          }
        }
      }
    }
  }
}

// ---------------- causal GQA flash attention (swapped-QK^T, in-reg softmax) ----
__global__ __launch_bounds__(256, 2) void attn_fwd(
    const u16* __restrict__ qkv, const u16* __restrict__ vT,
    u16* __restrict__ out) {
  __shared__ __align__(16) char smem[65536];  // dbuf: [buf]{K 16K, V 16K}

  const int tid = threadIdx.x;
  const int qt = blockIdx.x, h = blockIdx.y, b = blockIdx.z;
  const int hkv = h >> 2;
  const int q0 = qt * 128;
  const int wv = tid >> 6, lane = tid & 63;
  const int lr = lane & 15, lk = lane >> 4;

  auto stage = [&](int buf, int t) {
    const int kv0 = t * 64;
    char* kb_ = smem + buf * 32768;
    char* vb_ = kb_ + 16384;
#pragma unroll
    for (int i = 0; i < 4; ++i) {
      int c = i * 256 + tid, p = c * 16;
      int row = p >> 8, colb = (p & 255) ^ ((row & 7) << 4);
      gld_lds16(qkv + (size_t)(b * 2048 + kv0 + row) * 6144 + 4096 + hkv * 128 + (colb >> 1),
                kb_ + p);
    }
#pragma unroll
    for (int i = 0; i < 4; ++i) {
      int c = i * 256 + tid, p = c * 16;
      int row = p >> 7, colb = (p & 127) ^ ((row & 7) << 4);
      gld_lds16(vT + (size_t)((b * 8 + hkv) * 128 + row) * 2048 + kv0 + (colb >> 1),
                vb_ + p);
    }
  };

  bf16x8 qf[2][4];
#pragma unroll
  for (int qs = 0; qs < 2; ++qs) {
    const u16* qp = qkv + (size_t)(b * 2048 + q0 + wv * 32 + qs * 16 + lr) * 6144 +
                    h * 128 + lk * 8;
#pragma unroll
    for (int dc = 0; dc < 4; ++dc) qf[qs][dc] = *(const bf16x8*)(qp + dc * 32);
  }

  f32x4 o[2][8] = {};
  float mrun[2] = {-3.0e38f, -3.0e38f};
  float lsum[2] = {0.f, 0.f};
  const float sc = 0.08838834764831845f;

  const int nt = 2 * qt + 2;
  const int qbase_w = q0 + wv * 32;
  const int lkA = lr + 16 * (2 * (lk & 1) + (lk >> 1));
  const int lkB = lkA ^ 16;

  stage(0, 0);
  __syncthreads();
  for (int t = 0; t < nt; ++t) {
    const int buf = t & 1;
    if (t + 1 < nt) stage(buf ^ 1, t + 1);
    const int kv0 = t * 64;
    if (kv0 <= qbase_w + 31) {
      const char* kb_ = smem + buf * 32768;
      const char* vb_ = kb_ + 16384;

      f32x4 s[4][2];
#pragma unroll
      for (int cc = 0; cc < 4; ++cc) {
        const int krow = cc * 16 + lr;
        f32x4 a0 = {0.f, 0.f, 0.f, 0.f}, a1 = {0.f, 0.f, 0.f, 0.f};
#pragma unroll
        for (int dc = 0; dc < 4; ++dc) {
          bf16x8 kb = *(const bf16x8*)(kb_ + (krow << 8) +
                                       ((dc * 64 + lk * 16) ^ ((krow & 7) << 4)));
          a0 = MFMA16(kb, qf[0][dc], a0);
          a1 = MFMA16(kb, qf[1][dc], a1);
        }
        s[cc][0] = a0; s[cc][1] = a1;
      }

      const bool maskt = (kv0 + 63 > qbase_w);
#pragma unroll
      for (int cc = 0; cc < 4; ++cc)
#pragma unroll
        for (int qs = 0; qs < 2; ++qs)
#pragma unroll
          for (int j = 0; j < 4; ++j) {
            float v = s[cc][qs][j] * sc;
            if (maskt) {
              int kg = kv0 + cc * 16 + lk * 4 + j;
              int qg = qbase_w + qs * 16 + lr;
              if (kg > qg) v = -1.0e30f;
            }
            s[cc][qs][j] = v;
          }

      bf16x8 pfrag[2][2];
#pragma unroll
      for (int qs = 0; qs < 2; ++qs) {
        float mt = s[0][qs][0];
#pragma unroll
        for (int cc = 0; cc < 4; ++cc)
#pragma unroll
          for (int j = 0; j < 4; ++j) mt = fmaxf(mt, s[cc][qs][j]);
        mt = fmaxf(mt, __shfl_xor(mt, 16, 64));
        mt = fmaxf(mt, __shfl_xor(mt, 32, 64));
        const float mn = fmaxf(mrun[qs], mt);
        const float al = __expf(mrun[qs] - mn);
        mrun[qs] = mn;
        lsum[qs] *= al;
#pragma unroll
        for (int dc = 0; dc < 8; ++dc)
#pragma unroll
          for (int j = 0; j < 4; ++j) o[qs][dc][j] *= al;

        u32 pb[4][2];
        float ls = 0.f;
#pragma unroll
        for (int cc = 0; cc < 4; ++cc) {
          float p0 = __expf(s[cc][qs][0] - mn);
          float p1 = __expf(s[cc][qs][1] - mn);
          float p2 = __expf(s[cc][qs][2] - mn);
          float p3 = __expf(s[cc][qs][3] - mn);
          ls += (p0 + p1) + (p2 + p3);
          pb[cc][0] = pk2(p0, p1);
          pb[cc][1] = pk2(p2, p3);
        }
        lsum[qs] += ls;

#pragma unroll
        for (int ks = 0; ks < 2; ++ks) {
          const u32 e10 = (lk & 1) ? pb[ks * 2 + 1][0] : pb[ks * 2][0];
          const u32 e11 = (lk & 1) ? pb[ks * 2 + 1][1] : pb[ks * 2][1];
          const u32 e30 = (lk & 1) ? pb[ks * 2][0] : pb[ks * 2 + 1][0];
          const u32 e31 = (lk & 1) ? pb[ks * 2][1] : pb[ks * 2 + 1][1];
          const u32 r1 = __shfl((int)e10, lkA, 64);
          const u32 r2 = __shfl((int)e11, lkA, 64);
          const u32 r3 = __shfl((int)e30, lkB, 64);
          const u32 r4 = __shfl((int)e31, lkB, 64);
          u32x4 w;
          w[0] = (lk >> 1) ? r3 : r1;
          w[1] = (lk >> 1) ? r4 : r2;
          w[2] = (lk >> 1) ? r1 : r3;
          w[3] = (lk >> 1) ? r2 : r4;
          pfrag[qs][ks] = __builtin_bit_cast(bf16x8, w);
        }
      }

#pragma unroll
      for (int dc = 0; dc < 8; ++dc) {
        const int vrow = dc * 16 + lr;
#pragma unroll
        for (int ks = 0; ks < 2; ++ks) {
          bf16x8 vb = *(const bf16x8*)(vb_ + (vrow << 7) +
                                       ((ks * 64 + lk * 16) ^ ((vrow & 7) << 4)));
          o[0][dc] = MFMA16(vb, pfrag[0][ks], o[0][dc]);
          o[1][dc] = MFMA16(vb, pfrag[1][ks], o[1][dc]);
        }
      }
    }
    __syncthreads();
  }

  float rls[2];
#pragma unroll
  for (int qs = 0; qs < 2; ++qs) {
    float l = lsum[qs];
    l += __shfl_xor(l, 16, 64);
    l += __shfl_xor(l, 32, 64);
    rls[qs] = 1.0f / l;
  }
#pragma unroll
  for (int qs = 0; qs < 2; ++qs) {
    const int ql = wv * 32 + qs * 16 + lr;
#pragma unroll
    for (int dc = 0; dc < 8; ++dc) {
      u16x4 w;
#pragma unroll
      for (int j = 0; j < 4; ++j) w[j] = f2bf(o[qs][dc][j] * rls[qs]);
      *(u16x4*)(smem + ql * 256 + (((dc * 32 + lk * 8)) ^ ((ql & 7) << 4))) = w;
    }
  }
  __syncthreads();
#pragma unroll
  for (int i = 0; i < 8; ++i) {
    int c = i * 256 + tid;
    int row = c >> 4, ch = c & 15;
    u16x8 v = *(u16x8*)(smem + row * 256 + ((ch * 16) ^ ((row & 7) << 4)));
    *(u16x8*)(out + (size_t)(b * 2048 + q0 + row) * 4096 + h * 128 + ch * 8) = v;
  }
}

// ---------------- launcher ----------------
extern "C" void kernel_launch(void* const* d_in, const int* in_sizes, int n_in,
                              void* d_out, int out_size, void* d_ws, size_t ws_size,
                              hipStream_t stream) {
  const float* x  = (const float*)d_in[0];
  const float* w1 = (const float*)d_in[2];
  const float* b1 = (const float*)d_in[3];
  const float* w2 = (const float*)d_in[4];
  const float* b2 = (const float*)d_in[5];
  float* out = (float*)d_out;

  char* ws = (char*)d_ws;
  u16* xb   = (u16*)(ws);                  // x bf16      [4096][4096]
  u16* w1b  = (u16*)(ws + 33554432ul);     // Wqkv bf16   [6144][4096]
  u16* w2b  = (u16*)(ws + 83886080ul);     // out_w bf16  [4096][4096]
  u16* qkv  = (u16*)(ws + 117440512ul);    // qkv bf16    [4096][6144]
  u16* vT   = (u16*)(ws + 167772160ul);    // V^T bf16    [2][8][128][2048]
  u16* attnb = xb;                         // alias: x dead after GEMM1

  (void)hipFuncSetAttribute(reinterpret_cast<const void*>(gemm256<1>),
                            hipFuncAttributeMaxDynamicSharedMemorySize, 131072);
  (void)hipFuncSetAttribute(reinterpret_cast<const void*>(gemm256<0>),
                            hipFuncAttributeMaxDynamicSharedMemorySize, 131072);

  cvt_f32_bf16<<<2048, 256, 0, stream>>>(x,  xb,  16777216 / 8);
  cvt_f32_bf16<<<2048, 256, 0, stream>>>(w1, w1b, 25165824 / 8);
  gemm256<1><<<384, 512, 131072, stream>>>(xb, w1b, b1, qkv, vT, nullptr, 24);
  cvt_f32_bf16<<<2048, 256, 0, stream>>>(w2, w2b, 16777216 / 8);
  attn_fwd<<<dim3(16, 32, 2), 256, 0, stream>>>(qkv, vT, attnb);
  gemm256<0><<<256, 512, 131072, stream>>>(attnb, w2b, b2, nullptr, nullptr, out, 16);
}